// Round 1
// baseline (749.429 us; speedup 1.0000x reference)
//
#include <hip/hip_runtime.h>
#include <hip/hip_bf16.h>

#define S_SP 16384
#define NKV 512

typedef short short8 __attribute__((ext_vector_type(8)));
typedef float v4f   __attribute__((ext_vector_type(4)));

__device__ __forceinline__ unsigned short f2bf(float x){
  union { float f; unsigned u; } v; v.f = x;
  unsigned r = v.u + 0x7FFFu + ((v.u >> 16) & 1u);
  return (unsigned short)(r >> 16);
}
__device__ __forceinline__ float bf2f(unsigned short h){
  union { unsigned u; float f; } v; v.u = ((unsigned)h) << 16; return v.f;
}

// ---------------- K1: channel-LN stats (mean, 1/(std+eps)) for ctx & qs ----
__global__ __launch_bounds__(256) void k_stats(const float* __restrict__ ctx,
                                               const float* __restrict__ qs,
                                               float* __restrict__ MEAN,
                                               float* __restrict__ INV){
  __shared__ float r1[4][64];
  __shared__ float r2[4][64];
  int bx = blockIdx.x;
  int tt = bx >> 9; int b = (bx >> 8) & 1; int sc = bx & 255;
  int t = threadIdx.x;
  int sv = t & 63, cg = t >> 6;
  int s = sc*64 + sv;
  const float* src = (tt ? qs : ctx) + ((size_t)b*128 + cg*32)*S_SP + s;
  float sum = 0.f, ss = 0.f;
  #pragma unroll 8
  for (int c = 0; c < 32; c++){
    float v = src[(size_t)c*S_SP];
    sum += v; ss += v*v;
  }
  r1[cg][sv] = sum; r2[cg][sv] = ss;
  __syncthreads();
  if (t < 64){
    float sm = r1[0][t]+r1[1][t]+r1[2][t]+r1[3][t];
    float sq = r2[0][t]+r2[1][t]+r2[2][t]+r2[3][t];
    float mean = sm * 0.0078125f;
    float var  = fmaxf(sq * 0.0078125f - mean*mean, 0.f);
    int o = tt*2*S_SP + b*S_SP + sc*64 + t;
    MEAN[o] = mean;
    INV[o]  = 1.f/(sqrtf(var) + 1e-6f);
  }
}

// ---------------- K2: fused LN + q/k projection (fp32), l2norm epilogue ----
// q-blocks: write normalized q (bf16) + q_probe atomics.
// k-blocks: accumulate |k| axis-sums (D/H/W) via atomics; k not stored.
__global__ __launch_bounds__(256) void k_proj(
    const float* __restrict__ qsrc, const float* __restrict__ ctx,
    const float* __restrict__ wq, const float* __restrict__ wkv,
    const float* __restrict__ ctx_g, const float* __restrict__ ctx_b,
    const float* __restrict__ qs_g, const float* __restrict__ qs_b,
    const float* __restrict__ MEAN, const float* __restrict__ INV,
    unsigned short* __restrict__ QBF, float* __restrict__ QP,
    float* __restrict__ SUMD, float* __restrict__ SUMH, float* __restrict__ SUMW){
  __shared__ __align__(16) float wlds[128*64];
  __shared__ __align__(16) float xlds[32*132];
  __shared__ float invn[128];
  int bx = blockIdx.x;
  int st = bx & 127, head = (bx>>7)&7, b = (bx>>10)&1, isK = (bx>>11)&1;
  int t = threadIdx.x;
  int s0g = st*128;
  const float* src  = isK ? ctx   : qsrc;
  const float* gam  = isK ? ctx_g : qs_g;
  const float* bet  = isK ? ctx_b : qs_b;
  const float* wsrc = (isK ? wkv : wq) + (size_t)head*64*128;
  int tt = isK ? 0 : 1;
  const float* Mn = MEAN + tt*2*S_SP + b*S_SP + s0g;
  const float* Iv = INV  + tt*2*S_SP + b*S_SP + s0g;
  { // stage W [k][o]
    int oc = t>>2, ks = (t&3)*32;
    const float* wr = wsrc + oc*128 + ks;
    #pragma unroll 8
    for (int i=0;i<32;i++) wlds[(ks+i)*64 + oc] = wr[i];
  }
  int og = t>>4, sg = t&15;
  int o0 = og*4, sb = sg*8;
  float acc[4][8] = {};
  for (int kc=0; kc<4; kc++){
    __syncthreads();
    #pragma unroll
    for (int i=0;i<4;i++){ // stage LN'd x chunk [32k][128s]
      int f = t + 256*i;
      int kk = f>>5, scol = (f&31)*4;
      int cgl = kc*32 + kk;
      v4f xv = *(const v4f*)(src + ((size_t)(b*128 + cgl))*S_SP + s0g + scol);
      v4f mv = *(const v4f*)(Mn + scol);
      v4f iv = *(const v4f*)(Iv + scol);
      float gg = gam[cgl], bb = bet[cgl];
      v4f r;
      #pragma unroll
      for (int j=0;j<4;j++) r[j] = gg*(xv[j]-mv[j])*iv[j] + bb;
      *(v4f*)&xlds[kk*132 + scol] = r;
    }
    __syncthreads();
    #pragma unroll
    for (int kk=0;kk<32;kk++){
      v4f w4 = *(const v4f*)&wlds[(kc*32+kk)*64 + o0];
      v4f xa = *(const v4f*)&xlds[kk*132 + sb];
      v4f xb = *(const v4f*)&xlds[kk*132 + sb + 4];
      #pragma unroll
      for (int i=0;i<4;i++){
        float wv = w4[i];
        #pragma unroll
        for (int j=0;j<4;j++){
          acc[i][j]   += wv*xa[j];
          acc[i][j+4] += wv*xb[j];
        }
      }
    }
  }
  __syncthreads();
  float* ylds = wlds; // reuse as y[64 o][128 s]
  #pragma unroll
  for (int i=0;i<4;i++){
    v4f y0, y1;
    #pragma unroll
    for (int j=0;j<4;j++){ y0[j]=acc[i][j]; y1[j]=acc[i][j+4]; }
    *(v4f*)&ylds[(o0+i)*128 + sb]     = y0;
    *(v4f*)&ylds[(o0+i)*128 + sb + 4] = y1;
  }
  __syncthreads();
  if (t < 128){
    float ssum = 0.f;
    #pragma unroll 8
    for (int o=0;o<64;o++){ float v = ylds[o*128 + t]; ssum += v*v; }
    invn[t] = 1.f/fmaxf(sqrtf(ssum), 1e-12f);
  }
  __syncthreads();
  int bh = b*8 + head;
  if (!isK){
    int s = t>>1, c0 = (t&1)*32;
    float iv = invn[s];
    unsigned short* qp_ = QBF + ((size_t)bh*S_SP + s0g + s)*64 + c0;
    #pragma unroll
    for (int i=0;i<32;i+=2){
      unsigned pk = (unsigned)f2bf(ylds[(c0+i)*128+s]*iv)
                  | ((unsigned)f2bf(ylds[(c0+i+1)*128+s]*iv) << 16);
      *(unsigned*)(qp_ + i) = pk;
    }
    if (t < 64){
      int c = t; float sum = 0.f;
      #pragma unroll 4
      for (int j=0;j<128;j++){
        int sr = (j & ~31) | ((j + c) & 31); // bank-spread rotation within 32-blocks
        sum += ylds[c*128 + sr]*invn[sr];
      }
      atomicAdd(QP + bh*64 + c, sum);
    }
  } else {
    if (t < 64){
      int c = t;
      int d  = s0g >> 10;
      int h0 = (s0g >> 5) & 31;
      float accD = 0.f, accH[4] = {0,0,0,0}, accW[32];
      #pragma unroll
      for (int m=0;m<32;m++) accW[m] = 0.f;
      #pragma unroll
      for (int jo=0;jo<4;jo++){
        float hacc = 0.f;
        #pragma unroll
        for (int m=0;m<32;m++){
          int j = jo*32 + m;
          int sr = (j & ~31) | ((j + c) & 31); // w-index = (m+c)&31, h-index = jo (static)
          float v = fabsf(ylds[c*128 + sr]*invn[sr]);
          accD += v; hacc += v; accW[m] += v;
        }
        accH[jo] = hacc;
      }
      atomicAdd(SUMD + ((size_t)bh*64 + c)*16 + d, accD);
      #pragma unroll
      for (int i=0;i<4;i++) atomicAdd(SUMH + ((size_t)bh*64 + c)*32 + h0 + i, accH[i]);
      #pragma unroll
      for (int m=0;m<32;m++) atomicAdd(SUMW + ((size_t)bh*64 + c)*32 + ((m + c)&31), accW[m]);
    }
  }
}

// ---------------- K3: scores = qp . sums, top-8 per axis --------------------
__global__ __launch_bounds__(64) void k_topk(const float* __restrict__ QP,
    const float* __restrict__ SUMD, const float* __restrict__ SUMH,
    const float* __restrict__ SUMW, int* __restrict__ IDX){
  __shared__ float sc[80];
  int bh = blockIdx.x, c = threadIdx.x;
  float qpv = QP[bh*64 + c];
  const float* sd = SUMD + ((size_t)bh*64 + c)*16;
  const float* sh = SUMH + ((size_t)bh*64 + c)*32;
  const float* sw = SUMW + ((size_t)bh*64 + c)*32;
  for (int d=0; d<16; d++){
    float v = qpv * sd[d];
    #pragma unroll
    for (int m=32; m; m>>=1) v += __shfl_xor(v, m, 64);
    if (c == 0) sc[d] = v;
  }
  for (int h=0; h<32; h++){
    float v = qpv * sh[h];
    #pragma unroll
    for (int m=32; m; m>>=1) v += __shfl_xor(v, m, 64);
    if (c == 0) sc[16+h] = v;
  }
  for (int w=0; w<32; w++){
    float v = qpv * sw[w];
    #pragma unroll
    for (int m=32; m; m>>=1) v += __shfl_xor(v, m, 64);
    if (c == 0) sc[48+w] = v;
  }
  __syncthreads();
  if (c == 0){
    for (int a=0;a<3;a++){
      int n = a ? 32 : 16;
      int off = (a==0) ? 0 : (a==1 ? 16 : 48);
      for (int it=0; it<8; it++){
        int bi = 0; float bv = -3.4e38f;
        for (int i=0;i<n;i++){ float v = sc[off+i]; if (v > bv){ bv=v; bi=i; } }
        IDX[bh*24 + a*8 + it] = bi;
        sc[off+bi] = -3.4e38f;
      }
    }
  }
}

// ---------------- K4: recompute gathered k (l2norm, bf16) and v (bf16^T) ---
__global__ __launch_bounds__(256) void k_gather(const float* __restrict__ ctx,
    const float* __restrict__ wkv, const float* __restrict__ ctx_g,
    const float* __restrict__ ctx_b, const float* __restrict__ MEAN,
    const float* __restrict__ INV, const int* __restrict__ IDX,
    unsigned short* __restrict__ KG, unsigned short* __restrict__ VGT){
  __shared__ float wlds[64*129];
  __shared__ float xln[32*128];
  __shared__ int sidx[24];
  int bx = blockIdx.x;
  int bh = bx >> 5, jc = (bx >> 1) & 15, type = bx & 1;
  int head = bh & 7, b = bh >> 3;
  int t = threadIdx.x;
  if (t < 24) sidx[t] = IDX[bh*24 + t];
  {
    int oc = t>>2, ks = (t&3)*32;
    const float* wr = wkv + ((size_t)(type*512 + head*64 + oc))*128 + ks;
    #pragma unroll 8
    for (int i=0;i<32;i++) wlds[oc*129 + ks + i] = wr[i];
  }
  __syncthreads();
  {
    int jl = t>>3, seg = (t&7)*16;
    int jj = jc*32 + jl;
    int dsel = sidx[jj>>6], hsel = sidx[8 + ((jj>>3)&7)], wsel = sidx[16 + (jj&7)];
    int sj = dsel*1024 + hsel*32 + wsel;
    float mn = MEAN[b*S_SP + sj];
    float iv = INV[b*S_SP + sj];
    #pragma unroll
    for (int i=0;i<16;i++){
      int cc = seg + i;
      float raw = ctx[((size_t)(b*128 + cc))*S_SP + sj];
      xln[jl*128 + cc] = ctx_g[cc]*(raw - mn)*iv + ctx_b[cc];
    }
  }
  __syncthreads();
  int c = t & 63, jg = t >> 6;
  float accv[8] = {};
  #pragma unroll 4
  for (int k=0;k<128;k++){
    float wv = wlds[c*129 + k];
    #pragma unroll
    for (int m=0;m<8;m++) accv[m] += wv * xln[(jg + 4*m)*128 + k];
  }
  #pragma unroll
  for (int m=0;m<8;m++){
    int jj = jc*32 + jg + 4*m;
    float a = accv[m];
    if (type == 0){
      float sq = a*a;
      #pragma unroll
      for (int mm=32; mm; mm>>=1) sq += __shfl_xor(sq, mm, 64);
      float rn = 1.f/fmaxf(sqrtf(sq), 1e-12f);
      KG[((size_t)bh*NKV + jj)*64 + c] = f2bf(a*rn);
    } else {
      VGT[((size_t)bh*64 + c)*NKV + jj] = f2bf(a);
    }
  }
}

// ---------------- K5: attention, MFMA bf16, Nkv=512 in 4 chunks -------------
__global__ __launch_bounds__(256) void k_attn(const unsigned short* __restrict__ QBF,
    const unsigned short* __restrict__ KG, const unsigned short* __restrict__ VGT,
    unsigned short* __restrict__ AOUT){
  __shared__ __align__(16) unsigned short stage[128*72]; // K chunk / V chunk
  __shared__ __align__(16) unsigned short plds[4*16*132];
  int bx = blockIdx.x;
  int bh = bx >> 8, qt = bx & 255;
  int t = threadIdx.x;
  int wvi = t >> 6, lane = t & 63;
  int quad = lane >> 4, l15 = lane & 15;
  int q0 = qt*64 + wvi*16;
  short8 aq0, aq1;
  {
    const unsigned short* qp_ = QBF + ((size_t)bh*S_SP + q0 + l15)*64 + quad*8;
    union { uint4 u; short8 s; } u0, u1;
    u0.u = *(const uint4*)(qp_);
    u1.u = *(const uint4*)(qp_ + 32);
    aq0 = u0.s; aq1 = u1.s;
  }
  v4f acc[32];
  #pragma unroll
  for (int i=0;i<32;i++) acc[i] = (v4f){0.f,0.f,0.f,0.f};
  const unsigned short* kgb = KG + (size_t)bh*NKV*64;
  for (int ch=0; ch<4; ch++){
    __syncthreads();
    {
      int j = t >> 1, chf = (t & 1)*32;
      const unsigned short* sp = kgb + ((size_t)(ch*128 + j))*64 + chf;
      unsigned short* dp = stage + j*72 + chf;
      #pragma unroll
      for (int i=0;i<4;i++) *(uint4*)(dp + i*8) = *(const uint4*)(sp + i*8);
    }
    __syncthreads();
    #pragma unroll
    for (int jt=0; jt<8; jt++){
      const unsigned short* kr = stage + (jt*16 + l15)*72 + quad*8;
      union { uint4 u; short8 s; } b0, b1;
      b0.u = *(const uint4*)(kr);
      b1.u = *(const uint4*)(kr + 32);
      v4f a = acc[ch*8+jt];
      a = __builtin_amdgcn_mfma_f32_16x16x32_bf16(aq0, b0.s, a, 0, 0, 0);
      a = __builtin_amdgcn_mfma_f32_16x16x32_bf16(aq1, b1.s, a, 0, 0, 0);
      acc[ch*8+jt] = a;
    }
  }
  // softmax: row q = quad*4+r lives in this quad's 16 lanes
  float mx[4], ls[4];
  #pragma unroll
  for (int r=0;r<4;r++){
    float m = -3.4e38f;
    #pragma unroll
    for (int jt=0;jt<32;jt++) m = fmaxf(m, acc[jt][r]);
    m = fmaxf(m, __shfl_xor(m, 1, 64));
    m = fmaxf(m, __shfl_xor(m, 2, 64));
    m = fmaxf(m, __shfl_xor(m, 4, 64));
    m = fmaxf(m, __shfl_xor(m, 8, 64));
    mx[r] = m;
  }
  #pragma unroll
  for (int r=0;r<4;r++){
    float s = 0.f;
    #pragma unroll
    for (int jt=0;jt<32;jt++){
      float p = __expf(acc[jt][r] - mx[r]);
      acc[jt][r] = p; s += p;
    }
    s += __shfl_xor(s, 1, 64);
    s += __shfl_xor(s, 2, 64);
    s += __shfl_xor(s, 4, 64);
    s += __shfl_xor(s, 8, 64);
    ls[r] = s;
  }
  v4f out[4];
  #pragma unroll
  for (int i=0;i<4;i++) out[i] = (v4f){0.f,0.f,0.f,0.f};
  const unsigned short* vgb = VGT + (size_t)bh*64*NKV;
  unsigned short* pw = plds + wvi*(16*132);
  for (int ch=0; ch<4; ch++){
    __syncthreads();
    {
      int cc = t >> 2, jseg = (t & 3)*32;
      const unsigned short* sp = vgb + (size_t)cc*NKV + ch*128 + jseg;
      unsigned short* dp = stage + cc*136 + jseg;
      #pragma unroll
      for (int i=0;i<4;i++) *(uint4*)(dp + i*8) = *(const uint4*)(sp + i*8);
    }
    __syncthreads();
    #pragma unroll
    for (int jt=0;jt<8;jt++){ // P chunk: C-layout -> LDS [m][j]
      #pragma unroll
      for (int r=0;r<4;r++)
        pw[(quad*4+r)*132 + jt*16 + l15] = f2bf(acc[ch*8+jt][r]);
    }
    #pragma unroll
    for (int kt=0;kt<4;kt++){
      const unsigned short* pr = pw + l15*132 + kt*32 + quad*8;
      union { uint2 u[2]; short8 s; } pa;
      pa.u[0] = *(const uint2*)(pr);
      pa.u[1] = *(const uint2*)(pr + 4);
      #pragma unroll
      for (int nt=0;nt<4;nt++){
        const unsigned short* vr = stage + (nt*16 + l15)*136 + kt*32 + quad*8;
        union { uint4 u; short8 s; } vb; vb.u = *(const uint4*)(vr);
        out[nt] = __builtin_amdgcn_mfma_f32_16x16x32_bf16(pa.s, vb.s, out[nt], 0, 0, 0);
      }
    }
  }
  #pragma unroll
  for (int r=0;r<4;r++){
    float rs = 1.f/ls[r];
    size_t base = ((size_t)bh*S_SP + q0 + quad*4 + r)*64 + l15;
    #pragma unroll
    for (int nt=0;nt<4;nt++)
      AOUT[base + nt*16] = f2bf(out[nt][r]*rs);
  }
}

// ---------------- K6: out-projection (fp32) + LN + gamma*y + residual ------
__global__ __launch_bounds__(256) void k_out(const unsigned short* __restrict__ AOUT,
    const float* __restrict__ wout, const float* __restrict__ out_g,
    const float* __restrict__ out_b, const float* __restrict__ gamma,
    const float* __restrict__ qsrc, float* __restrict__ OUT){
  __shared__ __align__(16) float wl[64*132];
  __shared__ __align__(16) float xl[64*68];
  __shared__ float meanf[64], scalef[64];
  int bx = blockIdx.x;
  int b = bx >> 8, st = bx & 255;
  int s0 = st*64;
  int t = threadIdx.x;
  int cog = t >> 4, sg = t & 15;
  int co0 = cog*8, s1 = sg*4;
  float acc[8][4] = {};
  for (int chd=0; chd<8; chd++){
    __syncthreads();
    {
      int co = t >> 1, ks = (t & 1)*32;
      const float* wr = wout + (size_t)co*512 + chd*64 + ks;
      #pragma unroll 8
      for (int i=0;i<32;i++) wl[(ks+i)*132 + co] = wr[i];
    }
    {
      int si = t >> 2, cs = (t & 3)*16;
      const unsigned short* xr = AOUT + (((size_t)(b*8 + chd))*S_SP + s0 + si)*64 + cs;
      #pragma unroll
      for (int i=0;i<16;i++) xl[(cs+i)*68 + si] = bf2f(xr[i]);
    }
    __syncthreads();
    #pragma unroll
    for (int k=0;k<64;k++){
      v4f x4 = *(const v4f*)&xl[k*68 + s1];
      v4f w0 = *(const v4f*)&wl[k*132 + co0];
      v4f w1 = *(const v4f*)&wl[k*132 + co0 + 4];
      #pragma unroll
      for (int i=0;i<4;i++){
        #pragma unroll
        for (int j=0;j<4;j++){
          acc[i][j]   += w0[i]*x4[j];
          acc[i+4][j] += w1[i]*x4[j];
        }
      }
    }
  }
  __syncthreads();
  float* red1 = xl;
  float* red2 = xl + 64*17;
  #pragma unroll
  for (int j=0;j<4;j++){
    float s1v = 0.f, s2v = 0.f;
    #pragma unroll
    for (int i=0;i<8;i++){ float v = acc[i][j]; s1v += v; s2v += v*v; }
    red1[(s1+j)*17 + cog] = s1v;
    red2[(s1+j)*17 + cog] = s2v;
  }
  __syncthreads();
  if (t < 64){
    float m = 0.f, q = 0.f;
    #pragma unroll
    for (int g=0; g<16; g++){ m += red1[t*17+g]; q += red2[t*17+g]; }
    m *= 0.0078125f;
    float var = fmaxf(q*0.0078125f - m*m, 0.f);
    meanf[t]  = m;
    scalef[t] = 1.f/(sqrtf(var) + 1e-6f);
  }
  __syncthreads();
  float gs = gamma[0];
  #pragma unroll
  for (int i=0;i<8;i++){
    int co = co0 + i;
    float og = out_g[co], ob = out_b[co];
    size_t base = ((size_t)(b*128 + co))*S_SP + s0 + s1;
    v4f qv = *(const v4f*)(qsrc + base);
    v4f o;
    #pragma unroll
    for (int j=0;j<4;j++){
      float yn = (acc[i][j] - meanf[s1+j])*scalef[s1+j];
      o[j] = gs*(og*yn + ob) + qv[j];
    }
    *(v4f*)(OUT + base) = o;
  }
}

extern "C" void kernel_launch(void* const* d_in, const int* in_sizes, int n_in,
                              void* d_out, int out_size, void* d_ws, size_t ws_size,
                              hipStream_t stream){
  const float* qsrc  = (const float*)d_in[0];
  const float* ctx   = (const float*)d_in[1];
  const float* wq    = (const float*)d_in[2];
  const float* wkv   = (const float*)d_in[3];
  const float* wout  = (const float*)d_in[4];
  const float* ctx_g = (const float*)d_in[5];
  const float* ctx_b = (const float*)d_in[6];
  const float* qs_g  = (const float*)d_in[7];
  const float* qs_b  = (const float*)d_in[8];
  const float* out_g = (const float*)d_in[9];
  const float* out_b = (const float*)d_in[10];
  const float* gamma = (const float*)d_in[11];
  float* OUT = (float*)d_out;
  char* ws = (char*)d_ws;
  float* MEAN = (float*)(ws + 0);
  float* INV  = (float*)(ws + 262144);
  float* QP   = (float*)(ws + 524288);
  float* SUMD = (float*)(ws + 528384);
  float* SUMH = (float*)(ws + 593920);
  float* SUMW = (float*)(ws + 724992);
  int*   IDX  = (int*)(ws + 856064);
  unsigned short* QBF  = (unsigned short*)(ws + 857600);
  unsigned short* KG   = (unsigned short*)(ws + 34412032);
  unsigned short* VGT  = (unsigned short*)(ws + 35460608);
  unsigned short* AOUT = (unsigned short*)(ws + 36509184);

  hipMemsetAsync(ws + 524288, 0, 331776, stream); // QP + SUMD/H/W
  k_stats<<<1024, 256, 0, stream>>>(ctx, qsrc, MEAN, INV);
  k_proj<<<4096, 256, 0, stream>>>(qsrc, ctx, wq, wkv, ctx_g, ctx_b, qs_g, qs_b,
                                   MEAN, INV, QBF, QP, SUMD, SUMH, SUMW);
  k_topk<<<16, 64, 0, stream>>>(QP, SUMD, SUMH, SUMW, IDX);
  k_gather<<<512, 256, 0, stream>>>(ctx, wkv, ctx_g, ctx_b, MEAN, INV, IDX, KG, VGT);
  k_attn<<<4096, 256, 0, stream>>>(QBF, KG, VGT, AOUT);
  k_out<<<512, 256, 0, stream>>>(AOUT, wout, out_g, out_b, gamma, qsrc, OUT);
}

// Round 2
// 433.574 us; speedup vs baseline: 1.7285x; 1.7285x over previous
//
#include <hip/hip_runtime.h>
#include <hip/hip_bf16.h>

#define S_SP 16384
#define NKV 512

typedef short short8 __attribute__((ext_vector_type(8)));
typedef float v4f   __attribute__((ext_vector_type(4)));

__device__ __forceinline__ unsigned short f2bf(float x){
  union { float f; unsigned u; } v; v.f = x;
  unsigned r = v.u + 0x7FFFu + ((v.u >> 16) & 1u);
  return (unsigned short)(r >> 16);
}
__device__ __forceinline__ float bf2f(unsigned short h){
  union { unsigned u; float f; } v; v.u = ((unsigned)h) << 16; return v.f;
}

// ---------------- K1: channel-LN stats (mean, 1/(std+eps)) for ctx & qs ----
__global__ __launch_bounds__(256) void k_stats(const float* __restrict__ ctx,
                                               const float* __restrict__ qs,
                                               float* __restrict__ MEAN,
                                               float* __restrict__ INV){
  __shared__ float r1[4][64];
  __shared__ float r2[4][64];
  int bx = blockIdx.x;
  int tt = bx >> 9; int b = (bx >> 8) & 1; int sc = bx & 255;
  int t = threadIdx.x;
  int sv = t & 63, cg = t >> 6;
  int s = sc*64 + sv;
  const float* src = (tt ? qs : ctx) + ((size_t)b*128 + cg*32)*S_SP + s;
  float sum = 0.f, ss = 0.f;
  #pragma unroll 8
  for (int c = 0; c < 32; c++){
    float v = src[(size_t)c*S_SP];
    sum += v; ss += v*v;
  }
  r1[cg][sv] = sum; r2[cg][sv] = ss;
  __syncthreads();
  if (t < 64){
    float sm = r1[0][t]+r1[1][t]+r1[2][t]+r1[3][t];
    float sq = r2[0][t]+r2[1][t]+r2[2][t]+r2[3][t];
    float mean = sm * 0.0078125f;
    float var  = fmaxf(sq * 0.0078125f - mean*mean, 0.f);
    int o = tt*2*S_SP + b*S_SP + sc*64 + t;
    MEAN[o] = mean;
    INV[o]  = 1.f/(sqrtf(var) + 1e-6f);
  }
}

// ---------------- K2: fused LN + projection, W-broadcast register GEMM -----
// ISK=0: q projection -> QBF (bf16 normalized) + QP probe atomics (fp32)
// ISK=1: k projection -> direct fp32 score partials (needs QP complete)
template<int ISK>
__global__ __launch_bounds__(256) void k_projT(
    const float* __restrict__ src, const float* __restrict__ wmat,
    const float* __restrict__ gam, const float* __restrict__ bet,
    const float* __restrict__ MEAN, const float* __restrict__ INV,
    unsigned short* __restrict__ QBF, float* __restrict__ QP,
    float* __restrict__ SCORE){
  __shared__ __align__(16) float xlds[32*256];
  __shared__ __align__(16) float wlds[32*128];
  __shared__ float nbuf[4][256];
  __shared__ float ibuf[2][256];
  __shared__ float qpl[128];
  __shared__ float SCP[4][44];
  int bx = blockIdx.x;
  int og = bx & 3, stile = (bx>>2)&63, b = bx>>8;
  int s0 = stile*256;
  int t = threadIdx.x;
  int w = t>>6, lane = t&63;
  int ow0 = w*32;
  int tt = ISK ? 0 : 1;
  const float* Mn = MEAN + tt*32768 + b*16384 + s0;
  const float* Iv = INV  + tt*32768 + b*16384 + s0;
  const float* WB = wmat + (size_t)og*128*128;
  if (ISK){ if (t < 128) qpl[t] = QP[(b*8 + og*2)*64 + t]; }
  int col = lane*4;
  v4f mv = *(const v4f*)(Mn + col);
  v4f vv = *(const v4f*)(Iv + col);
  v4f acc[32];
  #pragma unroll
  for (int i=0;i<32;i++) acc[i] = (v4f){0.f,0.f,0.f,0.f};
  for (int kc=0;kc<4;kc++){
    __syncthreads();
    #pragma unroll
    for (int i=0;i<8;i++){ // stage LN'd x chunk [32 k][256 s]
      int kk = i*4 + w;
      int cgl = kc*32 + kk;
      v4f xv = *(const v4f*)(src + ((size_t)(b*128+cgl))*S_SP + s0 + col);
      float gg = gam[cgl], bb = bet[cgl];
      v4f r;
      #pragma unroll
      for (int j=0;j<4;j++) r[j] = gg*(xv[j]-mv[j])*vv[j] + bb;
      *(v4f*)&xlds[kk*256 + col] = r;
    }
    { // stage W chunk transposed -> [32 k][128 o]
      int oc = t>>1, ks0 = (t&1)*16;
      const float* wr = WB + (size_t)oc*128 + kc*32 + ks0;
      v4f w0 = *(const v4f*)wr, w1 = *(const v4f*)(wr+4);
      v4f w2 = *(const v4f*)(wr+8), w3 = *(const v4f*)(wr+12);
      #pragma unroll
      for (int i=0;i<4;i++){
        wlds[(ks0+i   )*128+oc]=w0[i];
        wlds[(ks0+i+4 )*128+oc]=w1[i];
        wlds[(ks0+i+8 )*128+oc]=w2[i];
        wlds[(ks0+i+12)*128+oc]=w3[i];
      }
    }
    __syncthreads();
    #pragma unroll 2
    for (int kk=0;kk<32;kk++){
      v4f xv = *(const v4f*)&xlds[kk*256 + col];
      #pragma unroll
      for (int o8=0;o8<8;o8++){
        v4f w4 = *(const v4f*)&wlds[kk*128 + ow0 + o8*4]; // uniform -> broadcast
        acc[o8*4+0] += xv*w4[0];
        acc[o8*4+1] += xv*w4[1];
        acc[o8*4+2] += xv*w4[2];
        acc[o8*4+3] += xv*w4[3];
      }
    }
  }
  // l2norm over 64 c (one head): partner waves (0,1)->head A, (2,3)->head B
  v4f ss = {0.f,0.f,0.f,0.f};
  #pragma unroll
  for (int o=0;o<32;o++) ss += acc[o]*acc[o];
  *(v4f*)&nbuf[w][col] = ss;
  __syncthreads();
  if (t < 256){
    float a0 = nbuf[0][t]+nbuf[1][t];
    float a1 = nbuf[2][t]+nbuf[3][t];
    ibuf[0][t] = 1.f/fmaxf(sqrtf(a0),1e-12f);
    ibuf[1][t] = 1.f/fmaxf(sqrtf(a1),1e-12f);
  }
  __syncthreads();
  int hl = w>>1;
  v4f iv4 = *(const v4f*)&ibuf[hl][col];
  int head = og*2 + hl, bh = b*8 + head;
  if (!ISK){
    #pragma unroll
    for (int o=0;o<32;o++) acc[o] *= iv4;
    #pragma unroll
    for (int j=0;j<4;j++){
      int s = s0 + col + j;
      unsigned short* dst = QBF + ((size_t)bh*S_SP + s)*64 + (w&1)*32;
      #pragma unroll
      for (int v=0;v<4;v++){
        uint4 pk;
        pk.x = (unsigned)f2bf(acc[v*8+0][j]) | ((unsigned)f2bf(acc[v*8+1][j])<<16);
        pk.y = (unsigned)f2bf(acc[v*8+2][j]) | ((unsigned)f2bf(acc[v*8+3][j])<<16);
        pk.z = (unsigned)f2bf(acc[v*8+4][j]) | ((unsigned)f2bf(acc[v*8+5][j])<<16);
        pk.w = (unsigned)f2bf(acc[v*8+6][j]) | ((unsigned)f2bf(acc[v*8+7][j])<<16);
        *(uint4*)(dst + v*8) = pk;
      }
    }
    float mine = 0.f;
    #pragma unroll
    for (int o=0;o<32;o++){
      float v = acc[o][0]+acc[o][1]+acc[o][2]+acc[o][3];
      v += __shfl_xor(v,1,64); v += __shfl_xor(v,2,64); v += __shfl_xor(v,4,64);
      v += __shfl_xor(v,8,64); v += __shfl_xor(v,16,64); v += __shfl_xor(v,32,64);
      if (lane == o) mine = v;
    }
    if (lane < 32) atomicAdd(QP + bh*64 + (w&1)*32 + lane, mine);
  } else {
    // block spatial tile = 1 d x 8 h x 32 w; lane covers (h=lane>>3, w=(lane&7)*4+j)
    v4f tj = {0.f,0.f,0.f,0.f};
    #pragma unroll
    for (int o=0;o<32;o++){
      float qw = qpl[ow0+o];
      v4f av;
      #pragma unroll
      for (int j=0;j<4;j++) av[j] = fabsf(acc[o][j]);
      tj += av*qw;
    }
    tj *= iv4;
    v4f twv = tj;
    #pragma unroll
    for (int m=8;m<=32;m<<=1){
      v4f o2;
      #pragma unroll
      for (int j=0;j<4;j++) o2[j] = __shfl_xor(twv[j], m, 64);
      twv += o2;
    }
    float th = tj[0]+tj[1]+tj[2]+tj[3];
    th += __shfl_xor(th,1,64); th += __shfl_xor(th,2,64); th += __shfl_xor(th,4,64);
    float td = twv[0]+twv[1]+twv[2]+twv[3];
    td += __shfl_xor(td,1,64); td += __shfl_xor(td,2,64); td += __shfl_xor(td,4,64);
    if (lane == 0) SCP[w][0] = td;
    if ((lane&7) == 0) SCP[w][1 + (lane>>3)] = th;
    if (lane < 8){
      #pragma unroll
      for (int j=0;j<4;j++) SCP[w][9 + lane*4 + j] = twv[j];
    }
    __syncthreads();
    if (t < 82){
      int hl2 = t/41, slot = t - hl2*41;
      float v = SCP[hl2*2][slot] + SCP[hl2*2+1][slot];
      int bh2 = b*8 + og*2 + hl2;
      int off;
      if (slot == 0) off = stile>>2;
      else if (slot < 9) off = 16 + (stile&3)*8 + (slot-1);
      else off = 48 + (slot-9);
      atomicAdd(SCORE + bh2*80 + off, v);
    }
  }
}

// ---------------- K3: top-8 per axis from accumulated scores ---------------
__global__ __launch_bounds__(64) void k_topk(const float* __restrict__ SCORE,
                                             int* __restrict__ IDX){
  int bh = blockIdx.x;
  if (threadIdx.x != 0) return;
  float sc[80];
  for (int i=0;i<80;i++) sc[i] = SCORE[bh*80+i];
  for (int a=0;a<3;a++){
    int n = a ? 32 : 16;
    int off = (a==0) ? 0 : (a==1 ? 16 : 48);
    for (int it=0; it<8; it++){
      int bi = 0; float bv = -3.4e38f;
      for (int i=0;i<n;i++){ float v = sc[off+i]; if (v > bv){ bv=v; bi=i; } }
      IDX[bh*24 + a*8 + it] = bi;
      sc[off+bi] = -3.4e38f;
    }
  }
}

// ---------------- K4: recompute gathered k (l2norm, bf16) and v (bf16^T) ---
__global__ __launch_bounds__(256) void k_gather(const float* __restrict__ ctx,
    const float* __restrict__ wkv, const float* __restrict__ ctx_g,
    const float* __restrict__ ctx_b, const float* __restrict__ MEAN,
    const float* __restrict__ INV, const int* __restrict__ IDX,
    unsigned short* __restrict__ KG, unsigned short* __restrict__ VGT){
  __shared__ float wlds[64*129];
  __shared__ float xln[32*128];
  __shared__ int sidx[24];
  int bx = blockIdx.x;
  int bh = bx >> 5, jc = (bx >> 1) & 15, type = bx & 1;
  int head = bh & 7, b = bh >> 3;
  int t = threadIdx.x;
  if (t < 24) sidx[t] = IDX[bh*24 + t];
  {
    int oc = t>>2, ks = (t&3)*32;
    const float* wr = wkv + ((size_t)(type*512 + head*64 + oc))*128 + ks;
    #pragma unroll 8
    for (int i=0;i<32;i++) wlds[oc*129 + ks + i] = wr[i];
  }
  __syncthreads();
  {
    int jl = t>>3, seg = (t&7)*16;
    int jj = jc*32 + jl;
    int dsel = sidx[jj>>6], hsel = sidx[8 + ((jj>>3)&7)], wsel = sidx[16 + (jj&7)];
    int sj = dsel*1024 + hsel*32 + wsel;
    float mn = MEAN[b*S_SP + sj];
    float iv = INV[b*S_SP + sj];
    #pragma unroll
    for (int i=0;i<16;i++){
      int cc = seg + i;
      float raw = ctx[((size_t)(b*128 + cc))*S_SP + sj];
      xln[jl*128 + cc] = ctx_g[cc]*(raw - mn)*iv + ctx_b[cc];
    }
  }
  __syncthreads();
  int c = t & 63, jg = t >> 6;
  float accv[8] = {};
  #pragma unroll 4
  for (int k=0;k<128;k++){
    float wv = wlds[c*129 + k];
    #pragma unroll
    for (int m=0;m<8;m++) accv[m] += wv * xln[(jg + 4*m)*128 + k];
  }
  #pragma unroll
  for (int m=0;m<8;m++){
    int jj = jc*32 + jg + 4*m;
    float a = accv[m];
    if (type == 0){
      float sq = a*a;
      #pragma unroll
      for (int mm=32; mm; mm>>=1) sq += __shfl_xor(sq, mm, 64);
      float rn = 1.f/fmaxf(sqrtf(sq), 1e-12f);
      KG[((size_t)bh*NKV + jj)*64 + c] = f2bf(a*rn);
    } else {
      VGT[((size_t)bh*64 + c)*NKV + jj] = f2bf(a);
    }
  }
}

// ---------------- K5: attention, MFMA bf16, Nkv=512 in 4 chunks -------------
__global__ __launch_bounds__(256) void k_attn(const unsigned short* __restrict__ QBF,
    const unsigned short* __restrict__ KG, const unsigned short* __restrict__ VGT,
    unsigned short* __restrict__ AOUT){
  __shared__ __align__(16) unsigned short stage[128*72]; // K chunk / V chunk
  __shared__ __align__(16) unsigned short plds[4*16*132];
  int bx = blockIdx.x;
  int bh = bx >> 8, qt = bx & 255;
  int t = threadIdx.x;
  int wvi = t >> 6, lane = t & 63;
  int quad = lane >> 4, l15 = lane & 15;
  int q0 = qt*64 + wvi*16;
  short8 aq0, aq1;
  {
    const unsigned short* qp_ = QBF + ((size_t)bh*S_SP + q0 + l15)*64 + quad*8;
    union { uint4 u; short8 s; } u0, u1;
    u0.u = *(const uint4*)(qp_);
    u1.u = *(const uint4*)(qp_ + 32);
    aq0 = u0.s; aq1 = u1.s;
  }
  v4f acc[32];
  #pragma unroll
  for (int i=0;i<32;i++) acc[i] = (v4f){0.f,0.f,0.f,0.f};
  const unsigned short* kgb = KG + (size_t)bh*NKV*64;
  for (int ch=0; ch<4; ch++){
    __syncthreads();
    {
      int j = t >> 1, chf = (t & 1)*32;
      const unsigned short* sp = kgb + ((size_t)(ch*128 + j))*64 + chf;
      unsigned short* dp = stage + j*72 + chf;
      #pragma unroll
      for (int i=0;i<4;i++) *(uint4*)(dp + i*8) = *(const uint4*)(sp + i*8);
    }
    __syncthreads();
    #pragma unroll
    for (int jt=0; jt<8; jt++){
      const unsigned short* kr = stage + (jt*16 + l15)*72 + quad*8;
      union { uint4 u; short8 s; } b0, b1;
      b0.u = *(const uint4*)(kr);
      b1.u = *(const uint4*)(kr + 32);
      v4f a = acc[ch*8+jt];
      a = __builtin_amdgcn_mfma_f32_16x16x32_bf16(aq0, b0.s, a, 0, 0, 0);
      a = __builtin_amdgcn_mfma_f32_16x16x32_bf16(aq1, b1.s, a, 0, 0, 0);
      acc[ch*8+jt] = a;
    }
  }
  float mx[4], ls[4];
  #pragma unroll
  for (int r=0;r<4;r++){
    float m = -3.4e38f;
    #pragma unroll
    for (int jt=0;jt<32;jt++) m = fmaxf(m, acc[jt][r]);
    m = fmaxf(m, __shfl_xor(m, 1, 64));
    m = fmaxf(m, __shfl_xor(m, 2, 64));
    m = fmaxf(m, __shfl_xor(m, 4, 64));
    m = fmaxf(m, __shfl_xor(m, 8, 64));
    mx[r] = m;
  }
  #pragma unroll
  for (int r=0;r<4;r++){
    float s = 0.f;
    #pragma unroll
    for (int jt=0;jt<32;jt++){
      float p = __expf(acc[jt][r] - mx[r]);
      acc[jt][r] = p; s += p;
    }
    s += __shfl_xor(s, 1, 64);
    s += __shfl_xor(s, 2, 64);
    s += __shfl_xor(s, 4, 64);
    s += __shfl_xor(s, 8, 64);
    ls[r] = s;
  }
  v4f out[4];
  #pragma unroll
  for (int i=0;i<4;i++) out[i] = (v4f){0.f,0.f,0.f,0.f};
  const unsigned short* vgb = VGT + (size_t)bh*64*NKV;
  unsigned short* pw = plds + wvi*(16*132);
  for (int ch=0; ch<4; ch++){
    __syncthreads();
    {
      int cc = t >> 2, jseg = (t & 3)*32;
      const unsigned short* sp = vgb + (size_t)cc*NKV + ch*128 + jseg;
      unsigned short* dp = stage + cc*136 + jseg;
      #pragma unroll
      for (int i=0;i<4;i++) *(uint4*)(dp + i*8) = *(const uint4*)(sp + i*8);
    }
    __syncthreads();
    #pragma unroll
    for (int jt=0;jt<8;jt++){
      #pragma unroll
      for (int r=0;r<4;r++)
        pw[(quad*4+r)*132 + jt*16 + l15] = f2bf(acc[ch*8+jt][r]);
    }
    #pragma unroll
    for (int kt=0;kt<4;kt++){
      const unsigned short* pr = pw + l15*132 + kt*32 + quad*8;
      union { uint2 u[2]; short8 s; } pa;
      pa.u[0] = *(const uint2*)(pr);
      pa.u[1] = *(const uint2*)(pr + 4);
      #pragma unroll
      for (int nt=0;nt<4;nt++){
        const unsigned short* vr = stage + (nt*16 + l15)*136 + kt*32 + quad*8;
        union { uint4 u; short8 s; } vb; vb.u = *(const uint4*)(vr);
        out[nt] = __builtin_amdgcn_mfma_f32_16x16x32_bf16(pa.s, vb.s, out[nt], 0, 0, 0);
      }
    }
  }
  #pragma unroll
  for (int r=0;r<4;r++){
    float rs = 1.f/ls[r];
    size_t base = ((size_t)bh*S_SP + q0 + quad*4 + r)*64 + l15;
    #pragma unroll
    for (int nt=0;nt<4;nt++)
      AOUT[base + nt*16] = f2bf(out[nt][r]*rs);
  }
}

// ---------------- K6: out-projection via MFMA bf16 + LN + residual ---------
__global__ __launch_bounds__(256) void k_out(const unsigned short* __restrict__ AOUT,
    const float* __restrict__ wout, const float* __restrict__ out_g,
    const float* __restrict__ out_b, const float* __restrict__ gamma,
    const float* __restrict__ qsrc, float* __restrict__ OUT){
  __shared__ __align__(16) unsigned short wl[128*40];
  __shared__ float lnp[4][2][64];
  __shared__ float mbuf[64], sbuf[64], ogl[128], obl[128];
  int bx = blockIdx.x; int b = bx>>8; int stile = bx&255; int s0 = stile*64;
  int t = threadIdx.x; int w = t>>6; int lane = t&63;
  int q = lane>>4; int l15 = lane&15;
  if (t < 128){ ogl[t] = out_g[t]; obl[t] = out_b[t]; }
  v4f acc[2][4];
  #pragma unroll
  for (int i=0;i<2;i++)
    #pragma unroll
    for (int j=0;j<4;j++) acc[i][j] = (v4f){0.f,0.f,0.f,0.f};
  for (int kt=0; kt<16; kt++){
    __syncthreads();
    { // stage W chunk [128 c][32 k] bf16, stride 40
      int c = t>>1, kb = (t&1)*16;
      const float* wr = wout + (size_t)c*512 + kt*32 + kb;
      v4f a0 = *(const v4f*)wr, a1 = *(const v4f*)(wr+4);
      v4f a2 = *(const v4f*)(wr+8), a3 = *(const v4f*)(wr+12);
      uint4 u0, u1;
      u0.x = (unsigned)f2bf(a0[0]) | ((unsigned)f2bf(a0[1])<<16);
      u0.y = (unsigned)f2bf(a0[2]) | ((unsigned)f2bf(a0[3])<<16);
      u0.z = (unsigned)f2bf(a1[0]) | ((unsigned)f2bf(a1[1])<<16);
      u0.w = (unsigned)f2bf(a1[2]) | ((unsigned)f2bf(a1[3])<<16);
      u1.x = (unsigned)f2bf(a2[0]) | ((unsigned)f2bf(a2[1])<<16);
      u1.y = (unsigned)f2bf(a2[2]) | ((unsigned)f2bf(a2[3])<<16);
      u1.z = (unsigned)f2bf(a3[0]) | ((unsigned)f2bf(a3[1])<<16);
      u1.w = (unsigned)f2bf(a3[2]) | ((unsigned)f2bf(a3[3])<<16);
      *(uint4*)&wl[c*40+kb]   = u0;
      *(uint4*)&wl[c*40+kb+8] = u1;
    }
    __syncthreads();
    short8 af[2];
    #pragma unroll
    for (int mt=0;mt<2;mt++){
      union { uint4 u; short8 s; } ua;
      ua.u = *(const uint4*)&wl[(w*32+mt*16+l15)*40 + q*8];
      af[mt] = ua.s;
    }
    int head = kt>>1; int cc0 = (kt&1)*32 + q*8;
    const unsigned short* bp = AOUT + ((size_t)((b*8+head)*S_SP + s0 + l15))*64 + cc0;
    #pragma unroll
    for (int nt=0;nt<4;nt++){
      union { uint4 u; short8 s; } ub;
      ub.u = *(const uint4*)(bp + (size_t)nt*16*64);
      #pragma unroll
      for (int mt=0;mt<2;mt++)
        acc[mt][nt] = __builtin_amdgcn_mfma_f32_16x16x32_bf16(af[mt], ub.s, acc[mt][nt], 0, 0, 0);
    }
  }
  // channel-LN stats over c=128 per s
  #pragma unroll
  for (int nt=0;nt<4;nt++){
    float p1 = 0.f, p2 = 0.f;
    #pragma unroll
    for (int mt=0;mt<2;mt++)
      #pragma unroll
      for (int r=0;r<4;r++){ float v = acc[mt][nt][r]; p1 += v; p2 += v*v; }
    p1 += __shfl_xor(p1,16,64); p1 += __shfl_xor(p1,32,64);
    p2 += __shfl_xor(p2,16,64); p2 += __shfl_xor(p2,32,64);
    if (q == 0){ lnp[w][0][nt*16+l15] = p1; lnp[w][1][nt*16+l15] = p2; }
  }
  __syncthreads();
  if (t < 64){
    float m = (lnp[0][0][t]+lnp[1][0][t]+lnp[2][0][t]+lnp[3][0][t]) * 0.0078125f;
    float qq = (lnp[0][1][t]+lnp[1][1][t]+lnp[2][1][t]+lnp[3][1][t]) * 0.0078125f;
    float var = fmaxf(qq - m*m, 0.f);
    mbuf[t] = m;
    sbuf[t] = 1.f/(sqrtf(var) + 1e-6f);
  }
  __syncthreads();
  float gs = gamma[0];
  #pragma unroll
  for (int nt=0;nt<4;nt++){
    int sl = nt*16 + l15;
    float mm = mbuf[sl], ssc = sbuf[sl];
    #pragma unroll
    for (int mt=0;mt<2;mt++){
      #pragma unroll
      for (int r=0;r<4;r++){
        int c = w*32 + mt*16 + q*4 + r;
        size_t adr = ((size_t)(b*128+c))*S_SP + s0 + sl;
        float yn = (acc[mt][nt][r]-mm)*ssc;
        OUT[adr] = gs*(ogl[c]*yn + obl[c]) + qsrc[adr];
      }
    }
  }
}

extern "C" void kernel_launch(void* const* d_in, const int* in_sizes, int n_in,
                              void* d_out, int out_size, void* d_ws, size_t ws_size,
                              hipStream_t stream){
  const float* qsrc  = (const float*)d_in[0];
  const float* ctx   = (const float*)d_in[1];
  const float* wq    = (const float*)d_in[2];
  const float* wkv   = (const float*)d_in[3];
  const float* wout  = (const float*)d_in[4];
  const float* ctx_g = (const float*)d_in[5];
  const float* ctx_b = (const float*)d_in[6];
  const float* qs_g  = (const float*)d_in[7];
  const float* qs_b  = (const float*)d_in[8];
  const float* out_g = (const float*)d_in[9];
  const float* out_b = (const float*)d_in[10];
  const float* gamma = (const float*)d_in[11];
  float* OUT = (float*)d_out;
  char* ws = (char*)d_ws;
  float* QP    = (float*)(ws);
  float* SCORE = (float*)(ws + 4096);
  float* MEAN  = (float*)(ws + 16384);
  float* INV   = (float*)(ws + 278528);
  int*   IDX   = (int*)(ws + 540672);
  unsigned short* QBF  = (unsigned short*)(ws + 544768);
  unsigned short* KG   = (unsigned short*)(ws + 34099200);
  unsigned short* VGT  = (unsigned short*)(ws + 35147776);
  unsigned short* AOUT = (unsigned short*)(ws + 36196352);

  hipMemsetAsync(ws, 0, 9216, stream); // QP + SCORE
  k_stats<<<1024, 256, 0, stream>>>(ctx, qsrc, MEAN, INV);
  k_projT<0><<<512, 256, 0, stream>>>(qsrc, wq, qs_g, qs_b, MEAN, INV, QBF, QP, SCORE);
  k_projT<1><<<512, 256, 0, stream>>>(ctx, wkv, ctx_g, ctx_b, MEAN, INV, QBF, QP, SCORE);
  k_topk<<<16, 64, 0, stream>>>(SCORE, IDX);
  k_gather<<<512, 256, 0, stream>>>(ctx, wkv, ctx_g, ctx_b, MEAN, INV, IDX, KG, VGT);
  k_attn<<<4096, 256, 0, stream>>>(QBF, KG, VGT, AOUT);
  k_out<<<512, 256, 0, stream>>>(AOUT, wout, out_g, out_b, gamma, qsrc, OUT);
}

// Round 3
// 340.986 us; speedup vs baseline: 2.1978x; 1.2715x over previous
//
#include <hip/hip_runtime.h>
#include <hip/hip_bf16.h>

#define S_SP 16384
#define NKV 512

typedef short short8 __attribute__((ext_vector_type(8)));
typedef float v4f   __attribute__((ext_vector_type(4)));

__device__ __forceinline__ unsigned short f2bf(float x){
  union { float f; unsigned u; } v; v.f = x;
  unsigned r = v.u + 0x7FFFu + ((v.u >> 16) & 1u);
  return (unsigned short)(r >> 16);
}
__device__ __forceinline__ float bf2f(unsigned short h){
  union { unsigned u; float f; } v; v.u = ((unsigned)h) << 16; return v.f;
}

#if defined(__has_builtin)
#if __has_builtin(__builtin_amdgcn_cvt_pk_bf16_f32)
#define HAVE_PKBF 1
#endif
#endif

__device__ __forceinline__ unsigned pk2(float a, float b){
#ifdef HAVE_PKBF
  typedef __bf16 bf16x2 __attribute__((ext_vector_type(2)));
  union { bf16x2 v; unsigned u; } r;
  r.v = __builtin_amdgcn_cvt_pk_bf16_f32(a, b);
  return r.u;
#else
  return (unsigned)f2bf(a) | ((unsigned)f2bf(b) << 16);
#endif
}

// ---------------- K1: channel-LN stats (mean, 1/(std+eps)) for ctx & qs ----
__global__ __launch_bounds__(256) void k_stats(const float* __restrict__ ctx,
                                               const float* __restrict__ qs,
                                               float* __restrict__ MEAN,
                                               float* __restrict__ INV){
  __shared__ float r1[4][64];
  __shared__ float r2[4][64];
  int bx = blockIdx.x;
  int tt = bx >> 9; int b = (bx >> 8) & 1; int sc = bx & 255;
  int t = threadIdx.x;
  int sv = t & 63, cg = t >> 6;
  int s = sc*64 + sv;
  const float* src = (tt ? qs : ctx) + ((size_t)b*128 + cg*32)*S_SP + s;
  float sum = 0.f, ss = 0.f;
  #pragma unroll 8
  for (int c = 0; c < 32; c++){
    float v = src[(size_t)c*S_SP];
    sum += v; ss += v*v;
  }
  r1[cg][sv] = sum; r2[cg][sv] = ss;
  __syncthreads();
  if (t < 64){
    float sm = r1[0][t]+r1[1][t]+r1[2][t]+r1[3][t];
    float sq = r2[0][t]+r2[1][t]+r2[2][t]+r2[3][t];
    float mean = sm * 0.0078125f;
    float var  = fmaxf(sq * 0.0078125f - mean*mean, 0.f);
    int o = tt*2*S_SP + b*S_SP + sc*64 + t;
    MEAN[o] = mean;
    INV[o]  = 1.f/(sqrtf(var) + 1e-6f);
  }
}

// ---------------- K2: fused LN + projection, W-broadcast register GEMM -----
template<int ISK>
__global__ __launch_bounds__(256) void k_projT(
    const float* __restrict__ src, const float* __restrict__ wmat,
    const float* __restrict__ gam, const float* __restrict__ bet,
    const float* __restrict__ MEAN, const float* __restrict__ INV,
    unsigned short* __restrict__ QBF, float* __restrict__ QP,
    float* __restrict__ SCORE){
  __shared__ __align__(16) float xlds[32*256];
  __shared__ __align__(16) float wlds[32*128];
  __shared__ float nbuf[4][256];
  __shared__ float ibuf[2][256];
  __shared__ float qpl[128];
  __shared__ float SCP[4][44];
  int bx = blockIdx.x;
  int og = bx & 3, stile = (bx>>2)&63, b = bx>>8;
  int s0 = stile*256;
  int t = threadIdx.x;
  int w = t>>6, lane = t&63;
  int ow0 = w*32;
  int tt = ISK ? 0 : 1;
  const float* Mn = MEAN + tt*32768 + b*16384 + s0;
  const float* Iv = INV  + tt*32768 + b*16384 + s0;
  const float* WB = wmat + (size_t)og*128*128;
  if (ISK){ if (t < 128) qpl[t] = QP[(b*8 + og*2)*64 + t]; }
  int col = lane*4;
  v4f mv = *(const v4f*)(Mn + col);
  v4f vv = *(const v4f*)(Iv + col);
  v4f acc[32];
  #pragma unroll
  for (int i=0;i<32;i++) acc[i] = (v4f){0.f,0.f,0.f,0.f};
  for (int kc=0;kc<4;kc++){
    __syncthreads();
    #pragma unroll
    for (int i=0;i<8;i++){
      int kk = i*4 + w;
      int cgl = kc*32 + kk;
      v4f xv = *(const v4f*)(src + ((size_t)(b*128+cgl))*S_SP + s0 + col);
      float gg = gam[cgl], bb = bet[cgl];
      v4f r;
      #pragma unroll
      for (int j=0;j<4;j++) r[j] = gg*(xv[j]-mv[j])*vv[j] + bb;
      *(v4f*)&xlds[kk*256 + col] = r;
    }
    {
      int oc = t>>1, ks0 = (t&1)*16;
      const float* wr = WB + (size_t)oc*128 + kc*32 + ks0;
      v4f w0 = *(const v4f*)wr, w1 = *(const v4f*)(wr+4);
      v4f w2 = *(const v4f*)(wr+8), w3 = *(const v4f*)(wr+12);
      #pragma unroll
      for (int i=0;i<4;i++){
        wlds[(ks0+i   )*128+oc]=w0[i];
        wlds[(ks0+i+4 )*128+oc]=w1[i];
        wlds[(ks0+i+8 )*128+oc]=w2[i];
        wlds[(ks0+i+12)*128+oc]=w3[i];
      }
    }
    __syncthreads();
    #pragma unroll 2
    for (int kk=0;kk<32;kk++){
      v4f xv = *(const v4f*)&xlds[kk*256 + col];
      #pragma unroll
      for (int o8=0;o8<8;o8++){
        v4f w4 = *(const v4f*)&wlds[kk*128 + ow0 + o8*4];
        acc[o8*4+0] += xv*w4[0];
        acc[o8*4+1] += xv*w4[1];
        acc[o8*4+2] += xv*w4[2];
        acc[o8*4+3] += xv*w4[3];
      }
    }
  }
  v4f ss = {0.f,0.f,0.f,0.f};
  #pragma unroll
  for (int o=0;o<32;o++) ss += acc[o]*acc[o];
  *(v4f*)&nbuf[w][col] = ss;
  __syncthreads();
  if (t < 256){
    float a0 = nbuf[0][t]+nbuf[1][t];
    float a1 = nbuf[2][t]+nbuf[3][t];
    ibuf[0][t] = 1.f/fmaxf(sqrtf(a0),1e-12f);
    ibuf[1][t] = 1.f/fmaxf(sqrtf(a1),1e-12f);
  }
  __syncthreads();
  int hl = w>>1;
  v4f iv4 = *(const v4f*)&ibuf[hl][col];
  int head = og*2 + hl, bh = b*8 + head;
  if (!ISK){
    #pragma unroll
    for (int o=0;o<32;o++) acc[o] *= iv4;
    #pragma unroll
    for (int j=0;j<4;j++){
      int s = s0 + col + j;
      unsigned short* dst = QBF + ((size_t)bh*S_SP + s)*64 + (w&1)*32;
      #pragma unroll
      for (int v=0;v<4;v++){
        uint4 pk;
        pk.x = pk2(acc[v*8+0][j], acc[v*8+1][j]);
        pk.y = pk2(acc[v*8+2][j], acc[v*8+3][j]);
        pk.z = pk2(acc[v*8+4][j], acc[v*8+5][j]);
        pk.w = pk2(acc[v*8+6][j], acc[v*8+7][j]);
        *(uint4*)(dst + v*8) = pk;
      }
    }
    float mine = 0.f;
    #pragma unroll
    for (int o=0;o<32;o++){
      float v = acc[o][0]+acc[o][1]+acc[o][2]+acc[o][3];
      v += __shfl_xor(v,1,64); v += __shfl_xor(v,2,64); v += __shfl_xor(v,4,64);
      v += __shfl_xor(v,8,64); v += __shfl_xor(v,16,64); v += __shfl_xor(v,32,64);
      if (lane == o) mine = v;
    }
    if (lane < 32) atomicAdd(QP + bh*64 + (w&1)*32 + lane, mine);
  } else {
    v4f tj = {0.f,0.f,0.f,0.f};
    #pragma unroll
    for (int o=0;o<32;o++){
      float qw = qpl[ow0+o];
      v4f av;
      #pragma unroll
      for (int j=0;j<4;j++) av[j] = fabsf(acc[o][j]);
      tj += av*qw;
    }
    tj *= iv4;
    v4f twv = tj;
    #pragma unroll
    for (int m=8;m<=32;m<<=1){
      v4f o2;
      #pragma unroll
      for (int j=0;j<4;j++) o2[j] = __shfl_xor(twv[j], m, 64);
      twv += o2;
    }
    float th = tj[0]+tj[1]+tj[2]+tj[3];
    th += __shfl_xor(th,1,64); th += __shfl_xor(th,2,64); th += __shfl_xor(th,4,64);
    float td = twv[0]+twv[1]+twv[2]+twv[3];
    td += __shfl_xor(td,1,64); td += __shfl_xor(td,2,64); td += __shfl_xor(td,4,64);
    if (lane == 0) SCP[w][0] = td;
    if ((lane&7) == 0) SCP[w][1 + (lane>>3)] = th;
    if (lane < 8){
      #pragma unroll
      for (int j=0;j<4;j++) SCP[w][9 + lane*4 + j] = twv[j];
    }
    __syncthreads();
    if (t < 82){
      int hl2 = t/41, slot = t - hl2*41;
      float v = SCP[hl2*2][slot] + SCP[hl2*2+1][slot];
      int bh2 = b*8 + og*2 + hl2;
      int off;
      if (slot == 0) off = stile>>2;
      else if (slot < 9) off = 16 + (stile&3)*8 + (slot-1);
      else off = 48 + (slot-9);
      atomicAdd(SCORE + bh2*80 + off, v);
    }
  }
}

// ---------------- K3: top-8 per axis from accumulated scores ---------------
__global__ __launch_bounds__(64) void k_topk(const float* __restrict__ SCORE,
                                             int* __restrict__ IDX){
  int bh = blockIdx.x;
  if (threadIdx.x != 0) return;
  float sc[80];
  for (int i=0;i<80;i++) sc[i] = SCORE[bh*80+i];
  for (int a=0;a<3;a++){
    int n = a ? 32 : 16;
    int off = (a==0) ? 0 : (a==1 ? 16 : 48);
    for (int it=0; it<8; it++){
      int bi = 0; float bv = -3.4e38f;
      for (int i=0;i<n;i++){ float v = sc[off+i]; if (v > bv){ bv=v; bi=i; } }
      IDX[bh*24 + a*8 + it] = bi;
      sc[off+bi] = -3.4e38f;
    }
  }
}

// ---------------- K4: recompute gathered k (l2norm, bf16) and v (bf16^T) ---
__global__ __launch_bounds__(256) void k_gather(const float* __restrict__ ctx,
    const float* __restrict__ wkv, const float* __restrict__ ctx_g,
    const float* __restrict__ ctx_b, const float* __restrict__ MEAN,
    const float* __restrict__ INV, const int* __restrict__ IDX,
    unsigned short* __restrict__ KG, unsigned short* __restrict__ VGT){
  __shared__ float wlds[64*129];
  __shared__ float xln[32*128];
  __shared__ int sidx[24];
  int bx = blockIdx.x;
  int bh = bx >> 5, jc = (bx >> 1) & 15, type = bx & 1;
  int head = bh & 7, b = bh >> 3;
  int t = threadIdx.x;
  if (t < 24) sidx[t] = IDX[bh*24 + t];
  {
    int oc = t>>2, ks = (t&3)*32;
    const float* wr = wkv + ((size_t)(type*512 + head*64 + oc))*128 + ks;
    #pragma unroll 8
    for (int i=0;i<32;i++) wlds[oc*129 + ks + i] = wr[i];
  }
  __syncthreads();
  {
    int jl = t>>3, seg = (t&7)*16;
    int jj = jc*32 + jl;
    int dsel = sidx[jj>>6], hsel = sidx[8 + ((jj>>3)&7)], wsel = sidx[16 + (jj&7)];
    int sj = dsel*1024 + hsel*32 + wsel;
    float mn = MEAN[b*S_SP + sj];
    float iv = INV[b*S_SP + sj];
    #pragma unroll
    for (int i=0;i<16;i++){
      int cc = seg + i;
      float raw = ctx[((size_t)(b*128 + cc))*S_SP + sj];
      xln[jl*128 + cc] = ctx_g[cc]*(raw - mn)*iv + ctx_b[cc];
    }
  }
  __syncthreads();
  int c = t & 63, jg = t >> 6;
  float accv[8] = {};
  #pragma unroll 4
  for (int k=0;k<128;k++){
    float wv = wlds[c*129 + k];
    #pragma unroll
    for (int m=0;m<8;m++) accv[m] += wv * xln[(jg + 4*m)*128 + k];
  }
  #pragma unroll
  for (int m=0;m<8;m++){
    int jj = jc*32 + jg + 4*m;
    float a = accv[m];
    if (type == 0){
      float sq = a*a;
      #pragma unroll
      for (int mm=32; mm; mm>>=1) sq += __shfl_xor(sq, mm, 64);
      float rn = 1.f/fmaxf(sqrtf(sq), 1e-12f);
      KG[((size_t)bh*NKV + jj)*64 + c] = f2bf(a*rn);
    } else {
      VGT[((size_t)bh*64 + c)*NKV + jj] = f2bf(a);
    }
  }
}

// ---------------- K5: attention, S^T=K.Q^T / O^T=V^T.P^T, fixed-max softmax -
// |sim|<=1 (l2-normed q,k) => softmax == exp(s-1)/sum exp(s-1): no max pass,
// no online rescale; chunks accumulate independently. Each wave owns 64 q.
__global__ __launch_bounds__(256) void k_attn(const unsigned short* __restrict__ QBF,
    const unsigned short* __restrict__ KG, const unsigned short* __restrict__ VGT,
    unsigned short* __restrict__ AOUT){
  __shared__ __align__(16) unsigned short kst[128*72];   // K chunk [j][c]
  __shared__ __align__(16) unsigned short vst[64*136];   // V chunk [c][j]
  __shared__ __align__(16) unsigned short pst[4][64*40]; // per-wave P [q][j 32+pad]
  int bx = blockIdx.x;
  int bh = bx >> 6, qb = bx & 63;
  int t = threadIdx.x;
  int wvi = t >> 6, lane = t & 63;
  int quad = lane >> 4, l15 = lane & 15;
  int q0 = qb*256 + wvi*64;
  const unsigned short* kgb = KG + (size_t)bh*NKV*64;
  const unsigned short* vgb = VGT + (size_t)bh*64*NKV;
  // Q fragments as B-operand: n=q=l15, k=c=quad*8+i
  short8 bq[4][2];
  #pragma unroll
  for (int qt=0; qt<4; qt++){
    const unsigned short* qp_ = QBF + ((size_t)bh*S_SP + q0 + qt*16 + l15)*64 + quad*8;
    union { uint4 u; short8 s; } u0, u1;
    u0.u = *(const uint4*)(qp_);
    u1.u = *(const uint4*)(qp_ + 32);
    bq[qt][0] = u0.s; bq[qt][1] = u1.s;
  }
  v4f oacc[4][4]; // [ct][qt]: O^T tile: col=q=l15, row=c=ct*16+quad*4+r
  #pragma unroll
  for (int i=0;i<4;i++)
    #pragma unroll
    for (int j=0;j<4;j++) oacc[i][j] = (v4f){0.f,0.f,0.f,0.f};
  float lsum[4] = {0.f,0.f,0.f,0.f};
  unsigned short* pw = pst[wvi];
  for (int ch=0; ch<4; ch++){
    __syncthreads();
    { // stage K chunk [128 j][64 c] -> stride 72
      int jl = t>>1, hf = (t&1)*32;
      const unsigned short* sp = kgb + (size_t)(ch*128 + jl)*64 + hf;
      unsigned short* dp = kst + jl*72 + hf;
      #pragma unroll
      for (int i=0;i<4;i++) *(uint4*)(dp + i*8) = *(const uint4*)(sp + i*8);
    }
    { // stage V chunk [64 c][128 j] -> stride 136
      int cc = t>>2, js = (t&3)*32;
      const unsigned short* sp = vgb + (size_t)cc*NKV + ch*128 + js;
      unsigned short* dp = vst + cc*136 + js;
      #pragma unroll
      for (int i=0;i<4;i++) *(uint4*)(dp + i*8) = *(const uint4*)(sp + i*8);
    }
    __syncthreads();
    #pragma unroll
    for (int sub=0; sub<4; sub++){ // 32 j per sub
      v4f s[2][4];
      #pragma unroll
      for (int j2=0; j2<2; j2++){
        int jt = sub*2 + j2;
        const unsigned short* kr = kst + (jt*16 + l15)*72 + quad*8;
        union { uint4 u; short8 s; } a0, a1;
        a0.u = *(const uint4*)(kr);
        a1.u = *(const uint4*)(kr + 32);
        #pragma unroll
        for (int qt=0; qt<4; qt++){
          v4f z = {0.f,0.f,0.f,0.f};
          z = __builtin_amdgcn_mfma_f32_16x16x32_bf16(a0.s, bq[qt][0], z, 0, 0, 0);
          z = __builtin_amdgcn_mfma_f32_16x16x32_bf16(a1.s, bq[qt][1], z, 0, 0, 0);
          s[j2][qt] = z;
        }
      }
      // exp(s-1), l-sum, packed P write: lane's 4 regs are contiguous in j
      #pragma unroll
      for (int j2=0; j2<2; j2++){
        #pragma unroll
        for (int qt=0; qt<4; qt++){
          v4f p;
          #pragma unroll
          for (int r=0;r<4;r++) p[r] = __expf(s[j2][qt][r] - 1.0f);
          lsum[qt] += p[0]+p[1]+p[2]+p[3];
          uint2 wv;
          wv.x = pk2(p[0], p[1]);
          wv.y = pk2(p[2], p[3]);
          *(uint2*)&pw[(qt*16 + l15)*40 + j2*16 + quad*4] = wv;
        }
      }
      // PV: O^T += V^T(64c x 32j) . P^T(32j x 64q)
      short8 bp[4];
      #pragma unroll
      for (int qt=0; qt<4; qt++){
        union { uint4 u; short8 s; } ub;
        ub.u = *(const uint4*)&pw[(qt*16 + l15)*40 + quad*8];
        bp[qt] = ub.s;
      }
      #pragma unroll
      for (int ct=0; ct<4; ct++){
        union { uint4 u; short8 s; } av;
        av.u = *(const uint4*)&vst[(ct*16 + l15)*136 + sub*32 + quad*8];
        #pragma unroll
        for (int qt=0; qt<4; qt++)
          oacc[ct][qt] = __builtin_amdgcn_mfma_f32_16x16x32_bf16(av.s, bp[qt], oacc[ct][qt], 0, 0, 0);
      }
    }
  }
  float rl[4];
  #pragma unroll
  for (int qt=0; qt<4; qt++){
    float l = lsum[qt];
    l += __shfl_xor(l, 16, 64);
    l += __shfl_xor(l, 32, 64);
    rl[qt] = 1.f/l;
  }
  #pragma unroll
  for (int qt=0; qt<4; qt++){
    #pragma unroll
    for (int ct=0; ct<4; ct++){
      v4f o = oacc[ct][qt];
      uint2 wv;
      wv.x = pk2(o[0]*rl[qt], o[1]*rl[qt]);
      wv.y = pk2(o[2]*rl[qt], o[3]*rl[qt]);
      *(uint2*)(AOUT + ((size_t)bh*S_SP + q0 + qt*16 + l15)*64 + ct*16 + quad*4) = wv;
    }
  }
}

// ---------------- K6: out-projection via MFMA bf16 + LN + residual ---------
__global__ __launch_bounds__(256) void k_out(const unsigned short* __restrict__ AOUT,
    const float* __restrict__ wout, const float* __restrict__ out_g,
    const float* __restrict__ out_b, const float* __restrict__ gamma,
    const float* __restrict__ qsrc, float* __restrict__ OUT){
  __shared__ __align__(16) unsigned short wl[128*40];
  __shared__ float lnp[4][2][64];
  __shared__ float mbuf[64], sbuf[64], ogl[128], obl[128];
  int bx = blockIdx.x; int b = bx>>8; int stile = bx&255; int s0 = stile*64;
  int t = threadIdx.x; int w = t>>6; int lane = t&63;
  int q = lane>>4; int l15 = lane&15;
  if (t < 128){ ogl[t] = out_g[t]; obl[t] = out_b[t]; }
  v4f acc[2][4];
  #pragma unroll
  for (int i=0;i<2;i++)
    #pragma unroll
    for (int j=0;j<4;j++) acc[i][j] = (v4f){0.f,0.f,0.f,0.f};
  for (int kt=0; kt<16; kt++){
    __syncthreads();
    {
      int c = t>>1, kb = (t&1)*16;
      const float* wr = wout + (size_t)c*512 + kt*32 + kb;
      v4f a0 = *(const v4f*)wr, a1 = *(const v4f*)(wr+4);
      v4f a2 = *(const v4f*)(wr+8), a3 = *(const v4f*)(wr+12);
      uint4 u0, u1;
      u0.x = pk2(a0[0], a0[1]); u0.y = pk2(a0[2], a0[3]);
      u0.z = pk2(a1[0], a1[1]); u0.w = pk2(a1[2], a1[3]);
      u1.x = pk2(a2[0], a2[1]); u1.y = pk2(a2[2], a2[3]);
      u1.z = pk2(a3[0], a3[1]); u1.w = pk2(a3[2], a3[3]);
      *(uint4*)&wl[c*40+kb]   = u0;
      *(uint4*)&wl[c*40+kb+8] = u1;
    }
    __syncthreads();
    short8 af[2];
    #pragma unroll
    for (int mt=0;mt<2;mt++){
      union { uint4 u; short8 s; } ua;
      ua.u = *(const uint4*)&wl[(w*32+mt*16+l15)*40 + q*8];
      af[mt] = ua.s;
    }
    int head = kt>>1; int cc0 = (kt&1)*32 + q*8;
    const unsigned short* bp = AOUT + ((size_t)((b*8+head)*S_SP + s0 + l15))*64 + cc0;
    #pragma unroll
    for (int nt=0;nt<4;nt++){
      union { uint4 u; short8 s; } ub;
      ub.u = *(const uint4*)(bp + (size_t)nt*16*64);
      #pragma unroll
      for (int mt=0;mt<2;mt++)
        acc[mt][nt] = __builtin_amdgcn_mfma_f32_16x16x32_bf16(af[mt], ub.s, acc[mt][nt], 0, 0, 0);
    }
  }
  #pragma unroll
  for (int nt=0;nt<4;nt++){
    float p1 = 0.f, p2 = 0.f;
    #pragma unroll
    for (int mt=0;mt<2;mt++)
      #pragma unroll
      for (int r=0;r<4;r++){ float v = acc[mt][nt][r]; p1 += v; p2 += v*v; }
    p1 += __shfl_xor(p1,16,64); p1 += __shfl_xor(p1,32,64);
    p2 += __shfl_xor(p2,16,64); p2 += __shfl_xor(p2,32,64);
    if (q == 0){ lnp[w][0][nt*16+l15] = p1; lnp[w][1][nt*16+l15] = p2; }
  }
  __syncthreads();
  if (t < 64){
    float m = (lnp[0][0][t]+lnp[1][0][t]+lnp[2][0][t]+lnp[3][0][t]) * 0.0078125f;
    float qq = (lnp[0][1][t]+lnp[1][1][t]+lnp[2][1][t]+lnp[3][1][t]) * 0.0078125f;
    float var = fmaxf(qq - m*m, 0.f);
    mbuf[t] = m;
    sbuf[t] = 1.f/(sqrtf(var) + 1e-6f);
  }
  __syncthreads();
  float gs = gamma[0];
  #pragma unroll
  for (int nt=0;nt<4;nt++){
    int sl = nt*16 + l15;
    float mm = mbuf[sl], ssc = sbuf[sl];
    #pragma unroll
    for (int mt=0;mt<2;mt++){
      #pragma unroll
      for (int r=0;r<4;r++){
        int c = w*32 + mt*16 + q*4 + r;
        size_t adr = ((size_t)(b*128+c))*S_SP + s0 + sl;
        float yn = (acc[mt][nt][r]-mm)*ssc;
        OUT[adr] = gs*(ogl[c]*yn + obl[c]) + qsrc[adr];
      }
    }
  }
}

extern "C" void kernel_launch(void* const* d_in, const int* in_sizes, int n_in,
                              void* d_out, int out_size, void* d_ws, size_t ws_size,
                              hipStream_t stream){
  const float* qsrc  = (const float*)d_in[0];
  const float* ctx   = (const float*)d_in[1];
  const float* wq    = (const float*)d_in[2];
  const float* wkv   = (const float*)d_in[3];
  const float* wout  = (const float*)d_in[4];
  const float* ctx_g = (const float*)d_in[5];
  const float* ctx_b = (const float*)d_in[6];
  const float* qs_g  = (const float*)d_in[7];
  const float* qs_b  = (const float*)d_in[8];
  const float* out_g = (const float*)d_in[9];
  const float* out_b = (const float*)d_in[10];
  const float* gamma = (const float*)d_in[11];
  float* OUT = (float*)d_out;
  char* ws = (char*)d_ws;
  float* QP    = (float*)(ws);
  float* SCORE = (float*)(ws + 4096);
  float* MEAN  = (float*)(ws + 16384);
  float* INV   = (float*)(ws + 278528);
  int*   IDX   = (int*)(ws + 540672);
  unsigned short* QBF  = (unsigned short*)(ws + 544768);
  unsigned short* KG   = (unsigned short*)(ws + 34099200);
  unsigned short* VGT  = (unsigned short*)(ws + 35147776);
  unsigned short* AOUT = (unsigned short*)(ws + 36196352);

  hipMemsetAsync(ws, 0, 9216, stream); // QP + SCORE
  k_stats<<<1024, 256, 0, stream>>>(ctx, qsrc, MEAN, INV);
  k_projT<0><<<512, 256, 0, stream>>>(qsrc, wq, qs_g, qs_b, MEAN, INV, QBF, QP, SCORE);
  k_projT<1><<<512, 256, 0, stream>>>(ctx, wkv, ctx_g, ctx_b, MEAN, INV, QBF, QP, SCORE);
  k_topk<<<16, 64, 0, stream>>>(SCORE, IDX);
  k_gather<<<512, 256, 0, stream>>>(ctx, wkv, ctx_g, ctx_b, MEAN, INV, IDX, KG, VGT);
  k_attn<<<1024, 256, 0, stream>>>(QBF, KG, VGT, AOUT);
  k_out<<<512, 256, 0, stream>>>(AOUT, wout, out_g, out_b, gamma, qsrc, OUT);
}